// Round 13
// baseline (316.660 us; speedup 1.0000x reference)
//
#include <hip/hip_runtime.h>
#include <hip/hip_bf16.h>
#include <math.h>
#include <stdint.h>

#define NO_N 100000
#define NR_N 1000
#define E_N  1000000
#define SB     250      // scatter blocks
#define SCHUNK 4000     // edges per scatter block (SB*SCHUNK == E_N)
#define KVP_TILES 1563  // ceil(NO_N/64)
#define KVP_BLKS 1024
#define MAXTILES 17008  // > NR_N + E_N/64

typedef short bf16x8 __attribute__((ext_vector_type(8)));
typedef float floatx4 __attribute__((ext_vector_type(4)));

__device__ __forceinline__ unsigned short bfu(float x) {
    union { __hip_bfloat16 h; unsigned short u; } c;
    c.h = __float2bfloat16(x);
    return c.u;
}
__device__ __forceinline__ float bflo(unsigned int u) {
    return __uint_as_float(u << 16);
}
__device__ __forceinline__ float bfhi(unsigned int u) {
    return __uint_as_float(u & 0xffff0000u);
}

// ---------------------------------------------------------------------------
// fat front-end: [0,250) prep_rider | 250 b1eff | [251,251+KVP_BLKS) kvp |
// then SB hist2 blocks.  All four mutually independent.
// ---------------------------------------------------------------------------
__global__ __launch_bounds__(256) void k_front(
    const float* __restrict__ xr,
    const float* __restrict__ Wq, const float* __restrict__ bq,
    const float* __restrict__ Wskip, const float* __restrict__ bskip,
    const float* __restrict__ We,
    float* __restrict__ q, float* __restrict__ skip, float* __restrict__ t,
    const float* __restrict__ W1, const float* __restrict__ b1,
    const float* __restrict__ omega, float* __restrict__ b1eff,
    const float* __restrict__ x,
    const float* __restrict__ Wk, const float* __restrict__ bk,
    const float* __restrict__ Wv, const float* __restrict__ bv,
    const float* __restrict__ Wp, const float* __restrict__ bp,
    unsigned short* __restrict__ kb, unsigned short* __restrict__ vb,
    unsigned short* __restrict__ pb,
    const int* __restrict__ ridx, int* __restrict__ ghist)
{
    __shared__ __align__(16) char smem[9216];
    const int tid = threadIdx.x;
    const int b = blockIdx.x;

    if (b < 250) {
        // ---------------- prep_rider ----------------
        float* sx = (float*)smem;            // [4][32]
        float* sq = sx + 128;                // [4][64]
        int rbase = b * 4;
        if (tid < 128) {
            int rl = tid >> 5, d = tid & 31;
            sx[rl * 32 + d] = xr[(rbase + rl) * 32 + d];
        }
        __syncthreads();
        int rl = tid >> 6, h = tid & 63;
        int r = rbase + rl;
        float aq = bq[h], as = bskip[h];
        #pragma unroll 4
        for (int d = 0; d < 32; ++d) {
            float xv = sx[rl * 32 + d];
            aq += xv * Wq[d * 64 + h];
            as += xv * Wskip[d * 64 + h];
        }
        sq[rl * 64 + h] = aq;
        q[r * 64 + h] = aq;
        skip[r * 64 + h] = as;
        __syncthreads();
        if (tid < 16) {
            int rl2 = tid >> 2, d = tid & 3;
            float acc = 0.f;
            for (int hh = 0; hh < 64; ++hh)
                acc += We[d * 64 + hh] * sq[rl2 * 64 + hh];
            t[(rbase + rl2) * 4 + d] = acc;
        }
    } else if (b == 250) {
        // ---------------- b1eff ----------------
        if (tid < 128) {
            float acc = b1[tid];
            #pragma unroll 4
            for (int j = 0; j < 32; ++j)
                acc += omega[j] * W1[(128 + j) * 128 + tid];
            b1eff[tid] = acc;
        }
    } else if (b < 251 + KVP_BLKS) {
        // ---------------- kvp (bf16 MFMA) ----------------
        unsigned short* sX = (unsigned short*)smem;   // 64*72
        const int wave = tid >> 6, lane = tid & 63;
        const int l15 = lane & 15, quad = lane >> 4;

        bf16x8 bfr[3][2];
        float bias[3];
        unsigned short* outT[3];
        int colc[3];
        #pragma unroll
        for (int ct = 0; ct < 3; ++ct) {
            int n = wave * 48 + ct * 16 + l15;
            int table = n >> 6, c = n & 63;
            const float* W  = (table == 0) ? Wk : (table == 1) ? Wv : Wp;
            const float* bb = (table == 0) ? bk : (table == 1) ? bv : bp;
            bias[ct] = bb[c];
            colc[ct] = c;
            outT[ct] = (table == 0) ? kb : (table == 1) ? vb : pb;
            #pragma unroll
            for (int kf = 0; kf < 2; ++kf) {
                bf16x8 f;
                #pragma unroll
                for (int j = 0; j < 8; ++j)
                    f[j] = (short)bfu(W[(size_t)(kf * 32 + quad * 8 + j) * 64 + c]);
                bfr[ct][kf] = f;
            }
        }

        const int srl = tid >> 2;
        const int sqt = (tid & 3) * 16;

        for (int tile = b - 251; tile < KVP_TILES; tile += KVP_BLKS) {
            int rowbase = tile * 64;
            {
                int row = rowbase + srl;
                unsigned short* dst = sX + srl * 72 + sqt;
                if (row < NO_N) {
                    const float4* src = (const float4*)(x + (size_t)row * 64 + sqt);
                    #pragma unroll
                    for (int i = 0; i < 4; ++i) {
                        float4 a = src[i];
                        ushort4 u = { bfu(a.x), bfu(a.y), bfu(a.z), bfu(a.w) };
                        *(ushort4*)(dst + i * 4) = u;
                    }
                } else {
                    ushort4 z = {0, 0, 0, 0};
                    #pragma unroll
                    for (int i = 0; i < 4; ++i) *(ushort4*)(dst + i * 4) = z;
                }
            }
            __syncthreads();

            floatx4 acc[4][3];
            #pragma unroll
            for (int rt = 0; rt < 4; ++rt)
                #pragma unroll
                for (int ct = 0; ct < 3; ++ct)
                    acc[rt][ct] = (floatx4){bias[ct], bias[ct], bias[ct], bias[ct]};

            #pragma unroll
            for (int rt = 0; rt < 4; ++rt) {
                const unsigned short* ar = sX + (size_t)(rt * 16 + l15) * 72 + quad * 8;
                bf16x8 a0 = *(const bf16x8*)(ar);
                bf16x8 a1 = *(const bf16x8*)(ar + 32);
                #pragma unroll
                for (int ct = 0; ct < 3; ++ct) {
                    floatx4 c = acc[rt][ct];
                    c = __builtin_amdgcn_mfma_f32_16x16x32_bf16(a0, bfr[ct][0], c, 0, 0, 0);
                    c = __builtin_amdgcn_mfma_f32_16x16x32_bf16(a1, bfr[ct][1], c, 0, 0, 0);
                    acc[rt][ct] = c;
                }
            }

            #pragma unroll
            for (int rt = 0; rt < 4; ++rt) {
                int rb = rowbase + rt * 16 + quad * 4;
                #pragma unroll
                for (int ct = 0; ct < 3; ++ct) {
                    unsigned short* o = outT[ct];
                    size_t cbase = colc[ct];
                    #pragma unroll
                    for (int g = 0; g < 4; ++g) {
                        int row = rb + g;
                        if (row < NO_N)
                            o[(size_t)row * 64 + cbase] = bfu(acc[rt][ct][g]);
                    }
                }
            }
            __syncthreads();
        }
    } else {
        // ---------------- hist2 ----------------
        int* hc = (int*)smem;                 // [NR_N]
        int hb = b - (251 + KVP_BLKS);
        for (int i = tid; i < NR_N; i += 256) hc[i] = 0;
        __syncthreads();
        int s = hb * SCHUNK;
        for (int i = s + tid; i < s + SCHUNK; i += 256)
            atomicAdd(&hc[ridx[i]], 1);
        __syncthreads();
        for (int i = tid; i < NR_N; i += 256)
            ghist[i * SB + hb] = hc[i];
    }
}

// ---------------------------------------------------------------------------
__global__ __launch_bounds__(256) void k_colscan(const int* __restrict__ ghist,
                                                 int* __restrict__ gpre,
                                                 int* __restrict__ counts)
{
    __shared__ int s[256];
    int tid = threadIdx.x, r = blockIdx.x;
    int v = (tid < SB) ? ghist[r * SB + tid] : 0;
    s[tid] = v;
    __syncthreads();
    for (int off = 1; off < 256; off <<= 1) {
        int tv = (tid >= off) ? s[tid - off] : 0;
        __syncthreads();
        s[tid] += tv;
        __syncthreads();
    }
    if (tid < SB) gpre[r * SB + tid] = s[tid] - v;
    if (tid == 255) counts[r] = s[255];
}

// scan over riders -> offsets; trec[t]={r,jb,jend} filled cooperatively
// (binary search over LDS tile-starts) instead of serial per-rider loops.
__global__ __launch_bounds__(1024) void k_scan(const int* __restrict__ counts,
                                               int* __restrict__ offsets,
                                               int* __restrict__ tilestart,
                                               int4* __restrict__ trec)
{
    __shared__ int s[1024];
    __shared__ int ofsL[NR_N];
    __shared__ int endL[NR_N];
    __shared__ int tsL[NR_N + 1];
    int tid = threadIdx.x;
    int c = (tid < NR_N) ? counts[tid] : 0;
    s[tid] = c;
    __syncthreads();
    for (int off = 1; off < 1024; off <<= 1) {
        int tv = (tid >= off) ? s[tid - off] : 0;
        __syncthreads();
        s[tid] += tv;
        __syncthreads();
    }
    int off0 = s[tid] - c;
    if (tid < NR_N) {
        offsets[tid] = off0;
        ofsL[tid] = off0;
        endL[tid] = off0 + c;
    }
    if (tid == NR_N - 1) offsets[NR_N] = s[tid];
    __syncthreads();
    int tc = (tid < NR_N) ? ((c + 63) >> 6) : 0;
    s[tid] = tc;
    __syncthreads();
    for (int off = 1; off < 1024; off <<= 1) {
        int tv = (tid >= off) ? s[tid - off] : 0;
        __syncthreads();
        s[tid] += tv;
        __syncthreads();
    }
    if (tid < NR_N) {
        int ts = s[tid] - tc;
        tsL[tid] = ts;
        tilestart[tid] = ts;
    }
    if (tid == NR_N - 1) {
        tsL[NR_N] = s[tid];
        tilestart[NR_N] = s[tid];
    }
    __syncthreads();
    int ntiles = tsL[NR_N];
    for (int t = tid; t < ntiles; t += 1024) {
        int lo = 0, hi = NR_N - 1;
        while (lo < hi) {                 // largest r with tsL[r] <= t
            int mid = (lo + hi + 1) >> 1;
            if (tsL[mid] <= t) lo = mid; else hi = mid - 1;
        }
        trec[t] = make_int4(lo, ofsL[lo] + ((t - tsL[lo]) << 6), endL[lo], 0);
    }
}

// ---------------------------------------------------------------------------
// scatter: spack (k_rider), so (k_edge2), rank (k_perm, coalesced in i)
// ---------------------------------------------------------------------------
__global__ __launch_bounds__(256) void k_scatter2(
    const int* __restrict__ ridx, const int* __restrict__ oidx,
    const float* __restrict__ ea, const float* __restrict__ t,
    const int* __restrict__ offsets, const int* __restrict__ gpre,
    int4* __restrict__ spack, int* __restrict__ so, int* __restrict__ rank)
{
    __shared__ int cur[NR_N];
    int tid = threadIdx.x, b = blockIdx.x;
    for (int i = tid; i < NR_N; i += 256)
        cur[i] = offsets[i] + gpre[i * SB + b];
    __syncthreads();
    int s = b * SCHUNK;
    for (int i = s + tid; i < s + SCHUNK; i += 256) {
        int r = ridx[i];
        int o = oidx[i];
        float4 e4 = *(const float4*)(ea + (size_t)i * 4);
        float4 t4 = *(const float4*)(t + r * 4);
        float h = e4.x * t4.x + e4.y * t4.y + e4.z * t4.z + e4.w * t4.w;
        int pos = atomicAdd(&cur[r], 1);
        int4 pk;
        pk.x = o;
        pk.y = __float_as_int(h);
        pk.z = (int)((unsigned)bfu(e4.x) | ((unsigned)bfu(e4.y) << 16));
        pk.w = (int)((unsigned)bfu(e4.z) | ((unsigned)bfu(e4.w) << 16));
        spack[pos] = pk;
        so[pos] = o;
        rank[i] = pos;
    }
}

// ---------------------------------------------------------------------------
// rider embedding + fused Br. 512 threads (8 waves): 4 blocks/CU co-resident.
// ---------------------------------------------------------------------------
__global__ __launch_bounds__(512) void k_rider(
    const int* __restrict__ offsets, const int4* __restrict__ spack,
    const float* __restrict__ q,
    const unsigned short* __restrict__ kb, const unsigned short* __restrict__ vb,
    const float* __restrict__ We, const float* __restrict__ skip,
    const float* __restrict__ W1, const float* __restrict__ b1eff,
    float* __restrict__ emb, float* __restrict__ Br)
{
    __shared__ float sQ[64];
    __shared__ int2 sOX[8][64];
    __shared__ float rv[8][64];
    __shared__ float re4[8][4];
    __shared__ float rd[8];

    int r = blockIdx.x;
    int wave = threadIdx.x >> 6, lane = threadIdx.x & 63;
    if (threadIdx.x < 64) sQ[threadIdx.x] = q[r * 64 + threadIdx.x];
    __syncthreads();

    int beg = offsets[r], end = offsets[r + 1];
    int cnt = end - beg;
    int chunk = (cnt + 7) >> 3;
    int s0 = beg + wave * chunk;
    int s1 = min(s0 + chunk, end);

    float aggv = 0.f, dsum = 0.f;
    float ag0 = 0.f, ag1 = 0.f, ag2 = 0.f, ag3 = 0.f;
    const float2* sQ2 = (const float2*)sQ;

    for (int jb = s0; jb < s1; jb += 64) {
        int j = jb + lane;
        bool valid = (j < s1);
        int4 pk = make_int4(0, 0, 0, 0);
        if (valid) pk = spack[j];
        int oo = pk.x;
        float h = __int_as_float(pk.y);

        const uint4* krow = (const uint4*)(kb + (size_t)oo * 64);
        uint4 K0 = krow[0], K1 = krow[1], K2 = krow[2], K3 = krow[3];
        uint4 K4 = krow[4], K5 = krow[5], K6 = krow[6], K7 = krow[7];
        float acc = h;
        #define DOT8(Kv, base) { \
            float2 qa = sQ2[(base) + 0]; \
            acc = fmaf(bflo(Kv.x), qa.x, acc); acc = fmaf(bfhi(Kv.x), qa.y, acc); \
            float2 qb = sQ2[(base) + 1]; \
            acc = fmaf(bflo(Kv.y), qb.x, acc); acc = fmaf(bfhi(Kv.y), qb.y, acc); \
            float2 qc = sQ2[(base) + 2]; \
            acc = fmaf(bflo(Kv.z), qc.x, acc); acc = fmaf(bfhi(Kv.z), qc.y, acc); \
            float2 qd = sQ2[(base) + 3]; \
            acc = fmaf(bflo(Kv.w), qd.x, acc); acc = fmaf(bfhi(Kv.w), qd.y, acc); }
        DOT8(K0, 0) DOT8(K1, 4) DOT8(K2, 8) DOT8(K3, 12)
        DOT8(K4, 16) DOT8(K5, 20) DOT8(K6, 24) DOT8(K7, 28)
        #undef DOT8

        float exv = valid ? __expf(acc * 0.125f) : 0.f;
        dsum += exv;
        unsigned int ez = (unsigned int)pk.z, ew = (unsigned int)pk.w;
        ag0 = fmaf(exv, bflo(ez), ag0);
        ag1 = fmaf(exv, bfhi(ez), ag1);
        ag2 = fmaf(exv, bflo(ew), ag2);
        ag3 = fmaf(exv, bfhi(ew), ag3);

        sOX[wave][lane] = make_int2(oo, __float_as_int(exv));

        int nn = min(s1 - jb, 64);
        int i = 0;
        for (; i + 8 <= nn; i += 8) {
            int2 x0 = sOX[wave][i + 0], x1 = sOX[wave][i + 1];
            int2 x2 = sOX[wave][i + 2], x3 = sOX[wave][i + 3];
            int2 x4 = sOX[wave][i + 4], x5 = sOX[wave][i + 5];
            int2 x6 = sOX[wave][i + 6], x7 = sOX[wave][i + 7];
            unsigned short u0 = vb[(size_t)x0.x * 64 + lane];
            unsigned short u1 = vb[(size_t)x1.x * 64 + lane];
            unsigned short u2 = vb[(size_t)x2.x * 64 + lane];
            unsigned short u3 = vb[(size_t)x3.x * 64 + lane];
            unsigned short u4 = vb[(size_t)x4.x * 64 + lane];
            unsigned short u5 = vb[(size_t)x5.x * 64 + lane];
            unsigned short u6 = vb[(size_t)x6.x * 64 + lane];
            unsigned short u7 = vb[(size_t)x7.x * 64 + lane];
            aggv = fmaf(__int_as_float(x0.y), __uint_as_float((unsigned int)u0 << 16), aggv);
            aggv = fmaf(__int_as_float(x1.y), __uint_as_float((unsigned int)u1 << 16), aggv);
            aggv = fmaf(__int_as_float(x2.y), __uint_as_float((unsigned int)u2 << 16), aggv);
            aggv = fmaf(__int_as_float(x3.y), __uint_as_float((unsigned int)u3 << 16), aggv);
            aggv = fmaf(__int_as_float(x4.y), __uint_as_float((unsigned int)u4 << 16), aggv);
            aggv = fmaf(__int_as_float(x5.y), __uint_as_float((unsigned int)u5 << 16), aggv);
            aggv = fmaf(__int_as_float(x6.y), __uint_as_float((unsigned int)u6 << 16), aggv);
            aggv = fmaf(__int_as_float(x7.y), __uint_as_float((unsigned int)u7 << 16), aggv);
        }
        for (; i < nn; ++i) {
            int2 xx = sOX[wave][i];
            unsigned short uu = vb[(size_t)xx.x * 64 + lane];
            aggv = fmaf(__int_as_float(xx.y), __uint_as_float((unsigned int)uu << 16), aggv);
        }
    }

    #pragma unroll
    for (int m = 1; m < 64; m <<= 1) {
        dsum += __shfl_xor(dsum, m);
        ag0 += __shfl_xor(ag0, m);
        ag1 += __shfl_xor(ag1, m);
        ag2 += __shfl_xor(ag2, m);
        ag3 += __shfl_xor(ag3, m);
    }

    rv[wave][lane] = aggv;
    if (lane == 0) {
        rd[wave] = dsum;
        re4[wave][0] = ag0; re4[wave][1] = ag1;
        re4[wave][2] = ag2; re4[wave][3] = ag3;
    }
    __syncthreads();
    if (threadIdx.x < 64) {
        int l = threadIdx.x;
        float av = 0.f, ds = 0.f, a0 = 0.f, a1 = 0.f, a2 = 0.f, a3 = 0.f;
        #pragma unroll
        for (int w = 0; w < 8; ++w) {
            av += rv[w][l]; ds += rd[w];
            a0 += re4[w][0]; a1 += re4[w][1]; a2 += re4[w][2]; a3 += re4[w][3];
        }
        float corr = a0 * We[0 * 64 + l] + a1 * We[1 * 64 + l]
                   + a2 * We[2 * 64 + l] + a3 * We[3 * 64 + l];
        float val = (av + corr) / (ds + 1e-16f) + skip[r * 64 + l];
        emb[r * 64 + l] = val;
        sQ[l] = val;                      // reuse sQ as emb row
    }
    __syncthreads();
    // fused Br: col c = tid (<128)
    if (threadIdx.x < 128) {
        int c = threadIdx.x;
        float a = b1eff[c];
        #pragma unroll 8
        for (int d = 0; d < 64; ++d)
            a = fmaf(sQ[d], W1[(size_t)(64 + d) * 128 + c], a);
        Br[r * 128 + c] = a;
    }
}

// ---------------------------------------------------------------------------
// per-edge scoring: WAVE-PER-TILE, lane-per-edge full-row gather (the k_rider
// phase-A pattern: 8 independent dwordx4 = 512 B in flight per lane).
// Lane l gathers edge (jb+l)'s full pb row, computes fp32 dot vs wave-uniform
// emb[r] (scalarized loads), stages its row into the wave's private LDS slab
// (stride 72 shorts, 16B-aligned rows), then the wave runs 4 row-tiles x 8
// col-tiles of MFMA with fused relu+W2 epilogue. Zero barriers.
// ---------------------------------------------------------------------------
__global__ __launch_bounds__(256) void k_edge2(
    const int* __restrict__ so, const int4* __restrict__ trec,
    const int* __restrict__ tilestart,
    const unsigned short* __restrict__ pb, const float* __restrict__ emb,
    const float* __restrict__ Br, const float* __restrict__ W1,
    const float* __restrict__ W2, const float* __restrict__ b2,
    float* __restrict__ tmp)
{
    __shared__ __align__(16) unsigned short sA[4][64 * 72];  // per-wave slab
    __shared__ float sDot[4][64];

    const int tid = threadIdx.x;
    const int wave = tid >> 6;
    const int lane = tid & 63;
    const int l15 = lane & 15;
    const int quad = lane >> 4;

    // persistent W1a fragments: all 128 cols per wave (ctl=0..7)
    bf16x8 bfr[8][2];
    float w2v[8];
    #pragma unroll
    for (int ctl = 0; ctl < 8; ++ctl) {
        int n = ctl * 16 + l15;
        w2v[ctl] = W2[n];
        #pragma unroll
        for (int kc = 0; kc < 2; ++kc) {
            bf16x8 f;
            #pragma unroll
            for (int j = 0; j < 8; ++j)
                f[j] = (short)bfu(W1[(size_t)(kc * 32 + quad * 8 + j) * 128 + n]);
            bfr[ctl][kc] = f;
        }
    }
    float b2v = b2[0];
    const int ntiles = tilestart[NR_N];

    unsigned short* myA = sA[wave];
    float* myDot = sDot[wave];

    for (int tile = blockIdx.x * 4 + wave; tile < ntiles; tile += gridDim.x * 4) {
        int4 rr = trec[tile];
        const int r = rr.x, jb = rr.y, jend = rr.z;

        // ---- lane-per-edge: full 128B pb row, 8 independent dwordx4 ----
        int o = so[min(jb + lane, jend - 1)];
        const uint4* prow = (const uint4*)(pb + (size_t)o * 64);
        uint4 R0 = prow[0], R1 = prow[1], R2 = prow[2], R3 = prow[3];
        uint4 R4 = prow[4], R5 = prow[5], R6 = prow[6], R7 = prow[7];

        // ---- fp32 dot vs wave-uniform emb row (scalarized loads) ----
        const float* er = emb + r * 64;
        float dotp = 0.f;
        #define DOTC(Rv, base) { \
            dotp = fmaf(bflo(Rv.x), er[(base) + 0], dotp); \
            dotp = fmaf(bfhi(Rv.x), er[(base) + 1], dotp); \
            dotp = fmaf(bflo(Rv.y), er[(base) + 2], dotp); \
            dotp = fmaf(bfhi(Rv.y), er[(base) + 3], dotp); \
            dotp = fmaf(bflo(Rv.z), er[(base) + 4], dotp); \
            dotp = fmaf(bfhi(Rv.z), er[(base) + 5], dotp); \
            dotp = fmaf(bflo(Rv.w), er[(base) + 6], dotp); \
            dotp = fmaf(bfhi(Rv.w), er[(base) + 7], dotp); }
        DOTC(R0, 0)  DOTC(R1, 8)  DOTC(R2, 16) DOTC(R3, 24)
        DOTC(R4, 32) DOTC(R5, 40) DOTC(R6, 48) DOTC(R7, 56)
        #undef DOTC
        myDot[lane] = dotp;

        // ---- stage own row (wave-private; rows at 144B stride, 16B aligned)
        {
            uint4* dst = (uint4*)(myA + lane * 72);
            dst[0] = R0; dst[1] = R1; dst[2] = R2; dst[3] = R3;
            dst[4] = R4; dst[5] = R5; dst[6] = R6; dst[7] = R7;
        }

        // rider-uniform Br slice (L1/L2-hot)
        float brv[8];
        #pragma unroll
        for (int ctl = 0; ctl < 8; ++ctl)
            brv[ctl] = Br[r * 128 + ctl * 16 + l15];

        // ---- MFMA over the wave's 64 edges x 128 cols, K=64 ----
        #pragma unroll
        for (int rt = 0; rt < 4; ++rt) {
            const unsigned short* ar = myA + (rt * 16 + l15) * 72 + quad * 8;
            bf16x8 a0 = *(const bf16x8*)(ar);
            bf16x8 a1 = *(const bf16x8*)(ar + 32);
            floatx4 s = (floatx4){0.f, 0.f, 0.f, 0.f};
            #pragma unroll
            for (int ctl = 0; ctl < 8; ++ctl) {
                floatx4 c = (floatx4){0.f, 0.f, 0.f, 0.f};
                c = __builtin_amdgcn_mfma_f32_16x16x32_bf16(a0, bfr[ctl][0], c, 0, 0, 0);
                c = __builtin_amdgcn_mfma_f32_16x16x32_bf16(a1, bfr[ctl][1], c, 0, 0, 0);
                #pragma unroll
                for (int g = 0; g < 4; ++g)
                    s[g] = fmaf(fmaxf(c[g] + brv[ctl], 0.f), w2v[ctl], s[g]);
            }
            #pragma unroll
            for (int m = 1; m < 16; m <<= 1) {
                s[0] += __shfl_xor(s[0], m);
                s[1] += __shfl_xor(s[1], m);
                s[2] += __shfl_xor(s[2], m);
                s[3] += __shfl_xor(s[3], m);
            }
            if (l15 == 0) {
                int rowb = rt * 16 + quad * 4;
                #pragma unroll
                for (int g = 0; g < 4; ++g) {
                    int pos = jb + rowb + g;
                    if (pos < jend) {
                        float v = s[g] + 0.125f * myDot[rowb + g] + b2v;
                        tmp[pos] = fminf(fmaxf(v, -10.f), 10.f);
                    }
                }
            }
        }
    }
}

// ---------------------------------------------------------------------------
// out[i] = tmp[rank[i]]  (rank coalesced read, tmp L2-resident gather)
// ---------------------------------------------------------------------------
__global__ __launch_bounds__(256) void k_perm(const int* __restrict__ rank,
                                              const float* __restrict__ tmp,
                                              float* __restrict__ out)
{
    int i = blockIdx.x * 256 + threadIdx.x;
    if (i < E_N) out[i] = tmp[rank[i]];
}

// ---------------------------------------------------------------------------
extern "C" void kernel_launch(void* const* d_in, const int* in_sizes, int n_in,
                              void* d_out, int out_size, void* d_ws, size_t ws_size,
                              hipStream_t stream)
{
    const float* x_order   = (const float*)d_in[0];
    const float* x_rider   = (const float*)d_in[1];
    const float* edge_attr = (const float*)d_in[2];
    const int*   order_idx = (const int*)d_in[3];
    const int*   rider_idx = (const int*)d_in[4];
    const float* omega     = (const float*)d_in[5];
    const float* Wk = (const float*)d_in[6];  const float* bk = (const float*)d_in[7];
    const float* Wq = (const float*)d_in[8];  const float* bq = (const float*)d_in[9];
    const float* Wv = (const float*)d_in[10]; const float* bv = (const float*)d_in[11];
    const float* We = (const float*)d_in[12];
    const float* Wskip = (const float*)d_in[13]; const float* bskip = (const float*)d_in[14];
    const float* Wp = (const float*)d_in[15]; const float* bp = (const float*)d_in[16];
    const float* W1 = (const float*)d_in[17]; const float* b1 = (const float*)d_in[18];
    const float* W2 = (const float*)d_in[19]; const float* b2 = (const float*)d_in[20];
    float* out = (float*)d_out;

    unsigned short* ws_kb = (unsigned short*)d_ws;
    unsigned short* ws_vb = ws_kb + (size_t)NO_N * 64;
    unsigned short* ws_pb = ws_vb + (size_t)NO_N * 64;
    int4* ws_spack = (int4*)(ws_pb + (size_t)NO_N * 64);
    float* ws_tmp  = (float*)ws_spack;              // alias: spack dead by k_edge2
    int*  ws_so    = (int*)(ws_spack + E_N);
    int*  ws_rank  = ws_so + E_N;
    float* wsf     = (float*)(ws_rank + E_N);
    float* ws_q    = wsf;
    float* ws_skip = ws_q + NR_N * 64;
    float* ws_emb  = ws_skip + NR_N * 64;
    float* ws_t    = ws_emb + NR_N * 64;
    float* ws_b1e  = ws_t + NR_N * 4;
    float* ws_Br   = ws_b1e + 128;
    int* ws_counts  = (int*)(ws_Br + NR_N * 128);
    int* ws_offsets = ws_counts + NR_N;
    int* ws_tilest  = ws_offsets + NR_N + 8;
    int* ws_ghist   = ws_tilest + NR_N + 8;
    int* ws_gpre    = ws_ghist + NR_N * SB;
    int4* ws_trec   = (int4*)(((uintptr_t)(ws_gpre + NR_N * SB) + 15) & ~(uintptr_t)15);

    k_front<<<251 + KVP_BLKS + SB, 256, 0, stream>>>(
        x_rider, Wq, bq, Wskip, bskip, We, ws_q, ws_skip, ws_t,
        W1, b1, omega, ws_b1e,
        x_order, Wk, bk, Wv, bv, Wp, bp, ws_kb, ws_vb, ws_pb,
        rider_idx, ws_ghist);
    k_colscan<<<NR_N, 256, 0, stream>>>(ws_ghist, ws_gpre, ws_counts);
    k_scan<<<1, 1024, 0, stream>>>(ws_counts, ws_offsets, ws_tilest, ws_trec);
    k_scatter2<<<SB, 256, 0, stream>>>(rider_idx, order_idx, edge_attr, ws_t,
                                       ws_offsets, ws_gpre, ws_spack, ws_so, ws_rank);
    k_rider<<<NR_N, 512, 0, stream>>>(ws_offsets, ws_spack, ws_q,
                                      ws_kb, ws_vb, We, ws_skip,
                                      W1, ws_b1e, ws_emb, ws_Br);
    k_edge2<<<2048, 256, 0, stream>>>(ws_so, ws_trec, ws_tilest,
                                      ws_pb, ws_emb, ws_Br, W1, W2, b2, ws_tmp);
    k_perm<<<(E_N + 255) / 256, 256, 0, stream>>>(ws_rank, ws_tmp, out);
}

// Round 14
// 301.494 us; speedup vs baseline: 1.0503x; 1.0503x over previous
//
#include <hip/hip_runtime.h>
#include <hip/hip_bf16.h>
#include <math.h>
#include <stdint.h>

#define NO_N 100000
#define NR_N 1000
#define E_N  1000000
#define SB     250      // scatter blocks
#define SCHUNK 4000     // edges per scatter block (SB*SCHUNK == E_N)
#define KVP_TILES 1563  // ceil(NO_N/64)
#define KVP_BLKS 1024
#define MAXTILES 17008  // > NR_N + E_N/64

typedef short bf16x8 __attribute__((ext_vector_type(8)));
typedef float floatx4 __attribute__((ext_vector_type(4)));

__device__ __forceinline__ unsigned short bfu(float x) {
    union { __hip_bfloat16 h; unsigned short u; } c;
    c.h = __float2bfloat16(x);
    return c.u;
}
__device__ __forceinline__ float bflo(unsigned int u) {
    return __uint_as_float(u << 16);
}
__device__ __forceinline__ float bfhi(unsigned int u) {
    return __uint_as_float(u & 0xffff0000u);
}

// ---------------------------------------------------------------------------
// fat front-end: [0,250) prep_rider | 250 b1eff | [251,251+KVP_BLKS) kvp |
// then SB hist2 blocks.  All four mutually independent.
// ---------------------------------------------------------------------------
__global__ __launch_bounds__(256) void k_front(
    const float* __restrict__ xr,
    const float* __restrict__ Wq, const float* __restrict__ bq,
    const float* __restrict__ Wskip, const float* __restrict__ bskip,
    const float* __restrict__ We,
    float* __restrict__ q, float* __restrict__ skip, float* __restrict__ t,
    const float* __restrict__ W1, const float* __restrict__ b1,
    const float* __restrict__ omega, float* __restrict__ b1eff,
    const float* __restrict__ x,
    const float* __restrict__ Wk, const float* __restrict__ bk,
    const float* __restrict__ Wv, const float* __restrict__ bv,
    const float* __restrict__ Wp, const float* __restrict__ bp,
    unsigned short* __restrict__ kb, unsigned short* __restrict__ vb,
    unsigned short* __restrict__ pb,
    const int* __restrict__ ridx, int* __restrict__ ghist)
{
    __shared__ __align__(16) char smem[9216];
    const int tid = threadIdx.x;
    const int b = blockIdx.x;

    if (b < 250) {
        // ---------------- prep_rider ----------------
        float* sx = (float*)smem;            // [4][32]
        float* sq = sx + 128;                // [4][64]
        int rbase = b * 4;
        if (tid < 128) {
            int rl = tid >> 5, d = tid & 31;
            sx[rl * 32 + d] = xr[(rbase + rl) * 32 + d];
        }
        __syncthreads();
        int rl = tid >> 6, h = tid & 63;
        int r = rbase + rl;
        float aq = bq[h], as = bskip[h];
        #pragma unroll 4
        for (int d = 0; d < 32; ++d) {
            float xv = sx[rl * 32 + d];
            aq += xv * Wq[d * 64 + h];
            as += xv * Wskip[d * 64 + h];
        }
        sq[rl * 64 + h] = aq;
        q[r * 64 + h] = aq;
        skip[r * 64 + h] = as;
        __syncthreads();
        if (tid < 16) {
            int rl2 = tid >> 2, d = tid & 3;
            float acc = 0.f;
            for (int hh = 0; hh < 64; ++hh)
                acc += We[d * 64 + hh] * sq[rl2 * 64 + hh];
            t[(rbase + rl2) * 4 + d] = acc;
        }
    } else if (b == 250) {
        // ---------------- b1eff ----------------
        if (tid < 128) {
            float acc = b1[tid];
            #pragma unroll 4
            for (int j = 0; j < 32; ++j)
                acc += omega[j] * W1[(128 + j) * 128 + tid];
            b1eff[tid] = acc;
        }
    } else if (b < 251 + KVP_BLKS) {
        // ---------------- kvp (bf16 MFMA) ----------------
        unsigned short* sX = (unsigned short*)smem;   // 64*72
        const int wave = tid >> 6, lane = tid & 63;
        const int l15 = lane & 15, quad = lane >> 4;

        bf16x8 bfr[3][2];
        float bias[3];
        unsigned short* outT[3];
        int colc[3];
        #pragma unroll
        for (int ct = 0; ct < 3; ++ct) {
            int n = wave * 48 + ct * 16 + l15;
            int table = n >> 6, c = n & 63;
            const float* W  = (table == 0) ? Wk : (table == 1) ? Wv : Wp;
            const float* bb = (table == 0) ? bk : (table == 1) ? bv : bp;
            bias[ct] = bb[c];
            colc[ct] = c;
            outT[ct] = (table == 0) ? kb : (table == 1) ? vb : pb;
            #pragma unroll
            for (int kf = 0; kf < 2; ++kf) {
                bf16x8 f;
                #pragma unroll
                for (int j = 0; j < 8; ++j)
                    f[j] = (short)bfu(W[(size_t)(kf * 32 + quad * 8 + j) * 64 + c]);
                bfr[ct][kf] = f;
            }
        }

        const int srl = tid >> 2;
        const int sqt = (tid & 3) * 16;

        for (int tile = b - 251; tile < KVP_TILES; tile += KVP_BLKS) {
            int rowbase = tile * 64;
            {
                int row = rowbase + srl;
                unsigned short* dst = sX + srl * 72 + sqt;
                if (row < NO_N) {
                    const float4* src = (const float4*)(x + (size_t)row * 64 + sqt);
                    #pragma unroll
                    for (int i = 0; i < 4; ++i) {
                        float4 a = src[i];
                        ushort4 u = { bfu(a.x), bfu(a.y), bfu(a.z), bfu(a.w) };
                        *(ushort4*)(dst + i * 4) = u;
                    }
                } else {
                    ushort4 z = {0, 0, 0, 0};
                    #pragma unroll
                    for (int i = 0; i < 4; ++i) *(ushort4*)(dst + i * 4) = z;
                }
            }
            __syncthreads();

            floatx4 acc[4][3];
            #pragma unroll
            for (int rt = 0; rt < 4; ++rt)
                #pragma unroll
                for (int ct = 0; ct < 3; ++ct)
                    acc[rt][ct] = (floatx4){bias[ct], bias[ct], bias[ct], bias[ct]};

            #pragma unroll
            for (int rt = 0; rt < 4; ++rt) {
                const unsigned short* ar = sX + (size_t)(rt * 16 + l15) * 72 + quad * 8;
                bf16x8 a0 = *(const bf16x8*)(ar);
                bf16x8 a1 = *(const bf16x8*)(ar + 32);
                #pragma unroll
                for (int ct = 0; ct < 3; ++ct) {
                    floatx4 c = acc[rt][ct];
                    c = __builtin_amdgcn_mfma_f32_16x16x32_bf16(a0, bfr[ct][0], c, 0, 0, 0);
                    c = __builtin_amdgcn_mfma_f32_16x16x32_bf16(a1, bfr[ct][1], c, 0, 0, 0);
                    acc[rt][ct] = c;
                }
            }

            #pragma unroll
            for (int rt = 0; rt < 4; ++rt) {
                int rb = rowbase + rt * 16 + quad * 4;
                #pragma unroll
                for (int ct = 0; ct < 3; ++ct) {
                    unsigned short* o = outT[ct];
                    size_t cbase = colc[ct];
                    #pragma unroll
                    for (int g = 0; g < 4; ++g) {
                        int row = rb + g;
                        if (row < NO_N)
                            o[(size_t)row * 64 + cbase] = bfu(acc[rt][ct][g]);
                    }
                }
            }
            __syncthreads();
        }
    } else {
        // ---------------- hist2 ----------------
        int* hc = (int*)smem;                 // [NR_N]
        int hb = b - (251 + KVP_BLKS);
        for (int i = tid; i < NR_N; i += 256) hc[i] = 0;
        __syncthreads();
        int s = hb * SCHUNK;
        for (int i = s + tid; i < s + SCHUNK; i += 256)
            atomicAdd(&hc[ridx[i]], 1);
        __syncthreads();
        for (int i = tid; i < NR_N; i += 256)
            ghist[i * SB + hb] = hc[i];
    }
}

// ---------------------------------------------------------------------------
__global__ __launch_bounds__(256) void k_colscan(const int* __restrict__ ghist,
                                                 int* __restrict__ gpre,
                                                 int* __restrict__ counts)
{
    __shared__ int s[256];
    int tid = threadIdx.x, r = blockIdx.x;
    int v = (tid < SB) ? ghist[r * SB + tid] : 0;
    s[tid] = v;
    __syncthreads();
    for (int off = 1; off < 256; off <<= 1) {
        int tv = (tid >= off) ? s[tid - off] : 0;
        __syncthreads();
        s[tid] += tv;
        __syncthreads();
    }
    if (tid < SB) gpre[r * SB + tid] = s[tid] - v;
    if (tid == 255) counts[r] = s[255];
}

// scan over riders -> offsets; trec[t]={r,jb,jend} filled cooperatively
// (binary search over LDS tile-starts).
__global__ __launch_bounds__(1024) void k_scan(const int* __restrict__ counts,
                                               int* __restrict__ offsets,
                                               int* __restrict__ tilestart,
                                               int4* __restrict__ trec)
{
    __shared__ int s[1024];
    __shared__ int ofsL[NR_N];
    __shared__ int endL[NR_N];
    __shared__ int tsL[NR_N + 1];
    int tid = threadIdx.x;
    int c = (tid < NR_N) ? counts[tid] : 0;
    s[tid] = c;
    __syncthreads();
    for (int off = 1; off < 1024; off <<= 1) {
        int tv = (tid >= off) ? s[tid - off] : 0;
        __syncthreads();
        s[tid] += tv;
        __syncthreads();
    }
    int off0 = s[tid] - c;
    if (tid < NR_N) {
        offsets[tid] = off0;
        ofsL[tid] = off0;
        endL[tid] = off0 + c;
    }
    if (tid == NR_N - 1) offsets[NR_N] = s[tid];
    __syncthreads();
    int tc = (tid < NR_N) ? ((c + 63) >> 6) : 0;
    s[tid] = tc;
    __syncthreads();
    for (int off = 1; off < 1024; off <<= 1) {
        int tv = (tid >= off) ? s[tid - off] : 0;
        __syncthreads();
        s[tid] += tv;
        __syncthreads();
    }
    if (tid < NR_N) {
        int ts = s[tid] - tc;
        tsL[tid] = ts;
        tilestart[tid] = ts;
    }
    if (tid == NR_N - 1) {
        tsL[NR_N] = s[tid];
        tilestart[NR_N] = s[tid];
    }
    __syncthreads();
    int ntiles = tsL[NR_N];
    for (int t = tid; t < ntiles; t += 1024) {
        int lo = 0, hi = NR_N - 1;
        while (lo < hi) {                 // largest r with tsL[r] <= t
            int mid = (lo + hi + 1) >> 1;
            if (tsL[mid] <= t) lo = mid; else hi = mid - 1;
        }
        trec[t] = make_int4(lo, ofsL[lo] + ((t - tsL[lo]) << 6), endL[lo], 0);
    }
}

// ---------------------------------------------------------------------------
// scatter: spack (k_rider), so (k_edge2), rank (k_perm, coalesced in i)
// ---------------------------------------------------------------------------
__global__ __launch_bounds__(256) void k_scatter2(
    const int* __restrict__ ridx, const int* __restrict__ oidx,
    const float* __restrict__ ea, const float* __restrict__ t,
    const int* __restrict__ offsets, const int* __restrict__ gpre,
    int4* __restrict__ spack, int* __restrict__ so, int* __restrict__ rank)
{
    __shared__ int cur[NR_N];
    int tid = threadIdx.x, b = blockIdx.x;
    for (int i = tid; i < NR_N; i += 256)
        cur[i] = offsets[i] + gpre[i * SB + b];
    __syncthreads();
    int s = b * SCHUNK;
    for (int i = s + tid; i < s + SCHUNK; i += 256) {
        int r = ridx[i];
        int o = oidx[i];
        float4 e4 = *(const float4*)(ea + (size_t)i * 4);
        float4 t4 = *(const float4*)(t + r * 4);
        float h = e4.x * t4.x + e4.y * t4.y + e4.z * t4.z + e4.w * t4.w;
        int pos = atomicAdd(&cur[r], 1);
        int4 pk;
        pk.x = o;
        pk.y = __float_as_int(h);
        pk.z = (int)((unsigned)bfu(e4.x) | ((unsigned)bfu(e4.y) << 16));
        pk.w = (int)((unsigned)bfu(e4.z) | ((unsigned)bfu(e4.w) << 16));
        spack[pos] = pk;
        so[pos] = o;
        rank[i] = pos;
    }
}

// ---------------------------------------------------------------------------
// rider embedding + fused Br. 512 threads (8 waves): 4 blocks/CU co-resident.
// ---------------------------------------------------------------------------
__global__ __launch_bounds__(512) void k_rider(
    const int* __restrict__ offsets, const int4* __restrict__ spack,
    const float* __restrict__ q,
    const unsigned short* __restrict__ kb, const unsigned short* __restrict__ vb,
    const float* __restrict__ We, const float* __restrict__ skip,
    const float* __restrict__ W1, const float* __restrict__ b1eff,
    float* __restrict__ emb, float* __restrict__ Br)
{
    __shared__ float sQ[64];
    __shared__ int2 sOX[8][64];
    __shared__ float rv[8][64];
    __shared__ float re4[8][4];
    __shared__ float rd[8];

    int r = blockIdx.x;
    int wave = threadIdx.x >> 6, lane = threadIdx.x & 63;
    if (threadIdx.x < 64) sQ[threadIdx.x] = q[r * 64 + threadIdx.x];
    __syncthreads();

    int beg = offsets[r], end = offsets[r + 1];
    int cnt = end - beg;
    int chunk = (cnt + 7) >> 3;
    int s0 = beg + wave * chunk;
    int s1 = min(s0 + chunk, end);

    float aggv = 0.f, dsum = 0.f;
    float ag0 = 0.f, ag1 = 0.f, ag2 = 0.f, ag3 = 0.f;
    const float2* sQ2 = (const float2*)sQ;

    for (int jb = s0; jb < s1; jb += 64) {
        int j = jb + lane;
        bool valid = (j < s1);
        int4 pk = make_int4(0, 0, 0, 0);
        if (valid) pk = spack[j];
        int oo = pk.x;
        float h = __int_as_float(pk.y);

        const uint4* krow = (const uint4*)(kb + (size_t)oo * 64);
        uint4 K0 = krow[0], K1 = krow[1], K2 = krow[2], K3 = krow[3];
        uint4 K4 = krow[4], K5 = krow[5], K6 = krow[6], K7 = krow[7];
        float acc = h;
        #define DOT8(Kv, base) { \
            float2 qa = sQ2[(base) + 0]; \
            acc = fmaf(bflo(Kv.x), qa.x, acc); acc = fmaf(bfhi(Kv.x), qa.y, acc); \
            float2 qb = sQ2[(base) + 1]; \
            acc = fmaf(bflo(Kv.y), qb.x, acc); acc = fmaf(bfhi(Kv.y), qb.y, acc); \
            float2 qc = sQ2[(base) + 2]; \
            acc = fmaf(bflo(Kv.z), qc.x, acc); acc = fmaf(bfhi(Kv.z), qc.y, acc); \
            float2 qd = sQ2[(base) + 3]; \
            acc = fmaf(bflo(Kv.w), qd.x, acc); acc = fmaf(bfhi(Kv.w), qd.y, acc); }
        DOT8(K0, 0) DOT8(K1, 4) DOT8(K2, 8) DOT8(K3, 12)
        DOT8(K4, 16) DOT8(K5, 20) DOT8(K6, 24) DOT8(K7, 28)
        #undef DOT8

        float exv = valid ? __expf(acc * 0.125f) : 0.f;
        dsum += exv;
        unsigned int ez = (unsigned int)pk.z, ew = (unsigned int)pk.w;
        ag0 = fmaf(exv, bflo(ez), ag0);
        ag1 = fmaf(exv, bfhi(ez), ag1);
        ag2 = fmaf(exv, bflo(ew), ag2);
        ag3 = fmaf(exv, bfhi(ew), ag3);

        sOX[wave][lane] = make_int2(oo, __float_as_int(exv));

        int nn = min(s1 - jb, 64);
        int i = 0;
        for (; i + 8 <= nn; i += 8) {
            int2 x0 = sOX[wave][i + 0], x1 = sOX[wave][i + 1];
            int2 x2 = sOX[wave][i + 2], x3 = sOX[wave][i + 3];
            int2 x4 = sOX[wave][i + 4], x5 = sOX[wave][i + 5];
            int2 x6 = sOX[wave][i + 6], x7 = sOX[wave][i + 7];
            unsigned short u0 = vb[(size_t)x0.x * 64 + lane];
            unsigned short u1 = vb[(size_t)x1.x * 64 + lane];
            unsigned short u2 = vb[(size_t)x2.x * 64 + lane];
            unsigned short u3 = vb[(size_t)x3.x * 64 + lane];
            unsigned short u4 = vb[(size_t)x4.x * 64 + lane];
            unsigned short u5 = vb[(size_t)x5.x * 64 + lane];
            unsigned short u6 = vb[(size_t)x6.x * 64 + lane];
            unsigned short u7 = vb[(size_t)x7.x * 64 + lane];
            aggv = fmaf(__int_as_float(x0.y), __uint_as_float((unsigned int)u0 << 16), aggv);
            aggv = fmaf(__int_as_float(x1.y), __uint_as_float((unsigned int)u1 << 16), aggv);
            aggv = fmaf(__int_as_float(x2.y), __uint_as_float((unsigned int)u2 << 16), aggv);
            aggv = fmaf(__int_as_float(x3.y), __uint_as_float((unsigned int)u3 << 16), aggv);
            aggv = fmaf(__int_as_float(x4.y), __uint_as_float((unsigned int)u4 << 16), aggv);
            aggv = fmaf(__int_as_float(x5.y), __uint_as_float((unsigned int)u5 << 16), aggv);
            aggv = fmaf(__int_as_float(x6.y), __uint_as_float((unsigned int)u6 << 16), aggv);
            aggv = fmaf(__int_as_float(x7.y), __uint_as_float((unsigned int)u7 << 16), aggv);
        }
        for (; i < nn; ++i) {
            int2 xx = sOX[wave][i];
            unsigned short uu = vb[(size_t)xx.x * 64 + lane];
            aggv = fmaf(__int_as_float(xx.y), __uint_as_float((unsigned int)uu << 16), aggv);
        }
    }

    #pragma unroll
    for (int m = 1; m < 64; m <<= 1) {
        dsum += __shfl_xor(dsum, m);
        ag0 += __shfl_xor(ag0, m);
        ag1 += __shfl_xor(ag1, m);
        ag2 += __shfl_xor(ag2, m);
        ag3 += __shfl_xor(ag3, m);
    }

    rv[wave][lane] = aggv;
    if (lane == 0) {
        rd[wave] = dsum;
        re4[wave][0] = ag0; re4[wave][1] = ag1;
        re4[wave][2] = ag2; re4[wave][3] = ag3;
    }
    __syncthreads();
    if (threadIdx.x < 64) {
        int l = threadIdx.x;
        float av = 0.f, ds = 0.f, a0 = 0.f, a1 = 0.f, a2 = 0.f, a3 = 0.f;
        #pragma unroll
        for (int w = 0; w < 8; ++w) {
            av += rv[w][l]; ds += rd[w];
            a0 += re4[w][0]; a1 += re4[w][1]; a2 += re4[w][2]; a3 += re4[w][3];
        }
        float corr = a0 * We[0 * 64 + l] + a1 * We[1 * 64 + l]
                   + a2 * We[2 * 64 + l] + a3 * We[3 * 64 + l];
        float val = (av + corr) / (ds + 1e-16f) + skip[r * 64 + l];
        emb[r * 64 + l] = val;
        sQ[l] = val;                      // reuse sQ as emb row
    }
    __syncthreads();
    // fused Br: col c = tid (<128)
    if (threadIdx.x < 128) {
        int c = threadIdx.x;
        float a = b1eff[c];
        #pragma unroll 8
        for (int d = 0; d < 64; ++d)
            a = fmaf(sQ[d], W1[(size_t)(64 + d) * 128 + c], a);
        Br[r * 128 + c] = a;
    }
}

// ---------------------------------------------------------------------------
// per-edge scoring: wave-per-tile, DIRECT global->MFMA A-fragment gathers.
// Lane (l15,quad) loads exactly its A-operand slices: for each row-tile rt,
// o_rt = __shfl(o_l, rt*16+l15), then two 16B loads at dims {quad*8, 32+quad*8}.
// No staging LDS, no transpose, no barriers in the loop. W1 fragments built
// once via coalesced LDS transpose (r12 pattern, measured cheap).
// ---------------------------------------------------------------------------
__global__ __launch_bounds__(256) void k_edge2(
    const int* __restrict__ so, const int4* __restrict__ trec,
    const int* __restrict__ tilestart,
    const unsigned short* __restrict__ pb, const float* __restrict__ emb,
    const float* __restrict__ Br, const float* __restrict__ W1,
    const float* __restrict__ W2, const float* __restrict__ b2,
    float* __restrict__ tmp)
{
    __shared__ __align__(16) unsigned short sW[128 * 72];  // W1a^T bf16

    const int tid = threadIdx.x;
    const int wave = tid >> 6;
    const int lane = tid & 63;
    const int l15 = lane & 15;
    const int quad = lane >> 4;

    // ---- setup: coalesced W1 -> LDS transpose -> ds_read_b128 fragments ----
    for (int idx = tid; idx < 64 * 128; idx += 256) {
        int k = idx >> 7, n = idx & 127;
        sW[n * 72 + k] = bfu(W1[idx]);
    }
    __syncthreads();

    bf16x8 bfr[8][2];
    float w2v[8];
    #pragma unroll
    for (int ctl = 0; ctl < 8; ++ctl) {
        int n = ctl * 16 + l15;
        w2v[ctl] = W2[n];
        #pragma unroll
        for (int kc = 0; kc < 2; ++kc)
            bfr[ctl][kc] = *(const bf16x8*)(sW + n * 72 + kc * 32 + quad * 8);
    }
    float b2v = b2[0];
    const int ntiles = tilestart[NR_N];

    union U4B { uint4 u; bf16x8 b; };

    for (int tile = blockIdx.x * 4 + wave; tile < ntiles; tile += gridDim.x * 4) {
        int4 rr = trec[tile];
        const int r = rr.x, jb = rr.y, jend = rr.z;

        // ---- edge ids (coalesced), then direct A-fragment gathers ----
        int o_l = so[min(jb + lane, jend - 1)];
        U4B A0[4], A1[4];
        #pragma unroll
        for (int rt = 0; rt < 4; ++rt) {
            int osrc = __shfl(o_l, rt * 16 + l15);
            const unsigned short* rowp = pb + (size_t)osrc * 64 + quad * 8;
            A0[rt].u = *(const uint4*)(rowp);        // dims quad*8 .. +8
            A1[rt].u = *(const uint4*)(rowp + 32);   // dims 32+quad*8 .. +8
        }

        // ---- fp32 dot partials vs wave-uniform emb row; reduce over quad ----
        const float* er = emb + r * 64;
        float dotv[4];
        #pragma unroll
        for (int rt = 0; rt < 4; ++rt) {
            const float* e0 = er + quad * 8;
            const float* e1 = er + 32 + quad * 8;
            float d = 0.f;
            d = fmaf(bflo(A0[rt].u.x), e0[0], d); d = fmaf(bfhi(A0[rt].u.x), e0[1], d);
            d = fmaf(bflo(A0[rt].u.y), e0[2], d); d = fmaf(bfhi(A0[rt].u.y), e0[3], d);
            d = fmaf(bflo(A0[rt].u.z), e0[4], d); d = fmaf(bfhi(A0[rt].u.z), e0[5], d);
            d = fmaf(bflo(A0[rt].u.w), e0[6], d); d = fmaf(bfhi(A0[rt].u.w), e0[7], d);
            d = fmaf(bflo(A1[rt].u.x), e1[0], d); d = fmaf(bfhi(A1[rt].u.x), e1[1], d);
            d = fmaf(bflo(A1[rt].u.y), e1[2], d); d = fmaf(bfhi(A1[rt].u.y), e1[3], d);
            d = fmaf(bflo(A1[rt].u.z), e1[4], d); d = fmaf(bfhi(A1[rt].u.z), e1[5], d);
            d = fmaf(bflo(A1[rt].u.w), e1[6], d); d = fmaf(bfhi(A1[rt].u.w), e1[7], d);
            d += __shfl_xor(d, 16);
            d += __shfl_xor(d, 32);
            dotv[rt] = d;      // full dot of edge rt*16+l15, valid on all lanes
        }

        // rider-uniform Br slice (L1/L2-hot)
        float brv[8];
        #pragma unroll
        for (int ctl = 0; ctl < 8; ++ctl)
            brv[ctl] = Br[r * 128 + ctl * 16 + l15];

        // ---- MFMA + fused relu/W2 epilogue per row-tile ----
        #pragma unroll
        for (int rt = 0; rt < 4; ++rt) {
            floatx4 s = (floatx4){0.f, 0.f, 0.f, 0.f};
            #pragma unroll
            for (int ctl = 0; ctl < 8; ++ctl) {
                floatx4 c = (floatx4){0.f, 0.f, 0.f, 0.f};
                c = __builtin_amdgcn_mfma_f32_16x16x32_bf16(A0[rt].b, bfr[ctl][0], c, 0, 0, 0);
                c = __builtin_amdgcn_mfma_f32_16x16x32_bf16(A1[rt].b, bfr[ctl][1], c, 0, 0, 0);
                #pragma unroll
                for (int g = 0; g < 4; ++g)
                    s[g] = fmaf(fmaxf(c[g] + brv[ctl], 0.f), w2v[ctl], s[g]);
            }
            #pragma unroll
            for (int m = 1; m < 16; m <<= 1) {
                s[0] += __shfl_xor(s[0], m);
                s[1] += __shfl_xor(s[1], m);
                s[2] += __shfl_xor(s[2], m);
                s[3] += __shfl_xor(s[3], m);
            }
            // dot values for rows quad*4+g (shuffles outside divergent branch)
            float sd0 = __shfl(dotv[rt], quad * 4 + 0);
            float sd1 = __shfl(dotv[rt], quad * 4 + 1);
            float sd2 = __shfl(dotv[rt], quad * 4 + 2);
            float sd3 = __shfl(dotv[rt], quad * 4 + 3);
            if (l15 == 0) {
                int rowb = rt * 16 + quad * 4;
                float sdv[4] = { sd0, sd1, sd2, sd3 };
                #pragma unroll
                for (int g = 0; g < 4; ++g) {
                    int pos = jb + rowb + g;
                    if (pos < jend) {
                        float v = s[g] + 0.125f * sdv[g] + b2v;
                        tmp[pos] = fminf(fmaxf(v, -10.f), 10.f);
                    }
                }
            }
        }
    }
}

// ---------------------------------------------------------------------------
// out[i] = tmp[rank[i]]  (rank coalesced read, tmp L2-resident gather)
// ---------------------------------------------------------------------------
__global__ __launch_bounds__(256) void k_perm(const int* __restrict__ rank,
                                              const float* __restrict__ tmp,
                                              float* __restrict__ out)
{
    int i = blockIdx.x * 256 + threadIdx.x;
    if (i < E_N) out[i] = tmp[rank[i]];
}

// ---------------------------------------------------------------------------
extern "C" void kernel_launch(void* const* d_in, const int* in_sizes, int n_in,
                              void* d_out, int out_size, void* d_ws, size_t ws_size,
                              hipStream_t stream)
{
    const float* x_order   = (const float*)d_in[0];
    const float* x_rider   = (const float*)d_in[1];
    const float* edge_attr = (const float*)d_in[2];
    const int*   order_idx = (const int*)d_in[3];
    const int*   rider_idx = (const int*)d_in[4];
    const float* omega     = (const float*)d_in[5];
    const float* Wk = (const float*)d_in[6];  const float* bk = (const float*)d_in[7];
    const float* Wq = (const float*)d_in[8];  const float* bq = (const float*)d_in[9];
    const float* Wv = (const float*)d_in[10]; const float* bv = (const float*)d_in[11];
    const float* We = (const float*)d_in[12];
    const float* Wskip = (const float*)d_in[13]; const float* bskip = (const float*)d_in[14];
    const float* Wp = (const float*)d_in[15]; const float* bp = (const float*)d_in[16];
    const float* W1 = (const float*)d_in[17]; const float* b1 = (const float*)d_in[18];
    const float* W2 = (const float*)d_in[19]; const float* b2 = (const float*)d_in[20];
    float* out = (float*)d_out;

    unsigned short* ws_kb = (unsigned short*)d_ws;
    unsigned short* ws_vb = ws_kb + (size_t)NO_N * 64;
    unsigned short* ws_pb = ws_vb + (size_t)NO_N * 64;
    int4* ws_spack = (int4*)(ws_pb + (size_t)NO_N * 64);
    float* ws_tmp  = (float*)ws_spack;              // alias: spack dead by k_edge2
    int*  ws_so    = (int*)(ws_spack + E_N);
    int*  ws_rank  = ws_so + E_N;
    float* wsf     = (float*)(ws_rank + E_N);
    float* ws_q    = wsf;
    float* ws_skip = ws_q + NR_N * 64;
    float* ws_emb  = ws_skip + NR_N * 64;
    float* ws_t    = ws_emb + NR_N * 64;
    float* ws_b1e  = ws_t + NR_N * 4;
    float* ws_Br   = ws_b1e + 128;
    int* ws_counts  = (int*)(ws_Br + NR_N * 128);
    int* ws_offsets = ws_counts + NR_N;
    int* ws_tilest  = ws_offsets + NR_N + 8;
    int* ws_ghist   = ws_tilest + NR_N + 8;
    int* ws_gpre    = ws_ghist + NR_N * SB;
    int4* ws_trec   = (int4*)(((uintptr_t)(ws_gpre + NR_N * SB) + 15) & ~(uintptr_t)15);

    k_front<<<251 + KVP_BLKS + SB, 256, 0, stream>>>(
        x_rider, Wq, bq, Wskip, bskip, We, ws_q, ws_skip, ws_t,
        W1, b1, omega, ws_b1e,
        x_order, Wk, bk, Wv, bv, Wp, bp, ws_kb, ws_vb, ws_pb,
        rider_idx, ws_ghist);
    k_colscan<<<NR_N, 256, 0, stream>>>(ws_ghist, ws_gpre, ws_counts);
    k_scan<<<1, 1024, 0, stream>>>(ws_counts, ws_offsets, ws_tilest, ws_trec);
    k_scatter2<<<SB, 256, 0, stream>>>(rider_idx, order_idx, edge_attr, ws_t,
                                       ws_offsets, ws_gpre, ws_spack, ws_so, ws_rank);
    k_rider<<<NR_N, 512, 0, stream>>>(ws_offsets, ws_spack, ws_q,
                                      ws_kb, ws_vb, We, ws_skip,
                                      W1, ws_b1e, ws_emb, ws_Br);
    k_edge2<<<1024, 256, 0, stream>>>(ws_so, ws_trec, ws_tilest,
                                      ws_pb, ws_emb, ws_Br, W1, W2, b2, ws_tmp);
    k_perm<<<(E_N + 255) / 256, 256, 0, stream>>>(ws_rank, ws_tmp, out);
}

// Round 15
// 287.770 us; speedup vs baseline: 1.1004x; 1.0477x over previous
//
#include <hip/hip_runtime.h>
#include <hip/hip_bf16.h>
#include <math.h>
#include <stdint.h>

#define NO_N 100000
#define NR_N 1000
#define E_N  1000000
#define SB     250      // scatter blocks
#define SCHUNK 4000     // edges per scatter block (SB*SCHUNK == E_N)
#define KVP_TILES 1563  // ceil(NO_N/64)
#define KVP_BLKS 1024
#define MAXTILES 17008  // > NR_N + E_N/64

typedef short bf16x8 __attribute__((ext_vector_type(8)));
typedef float floatx4 __attribute__((ext_vector_type(4)));

__device__ __forceinline__ unsigned short bfu(float x) {
    union { __hip_bfloat16 h; unsigned short u; } c;
    c.h = __float2bfloat16(x);
    return c.u;
}
__device__ __forceinline__ float bflo(unsigned int u) {
    return __uint_as_float(u << 16);
}
__device__ __forceinline__ float bfhi(unsigned int u) {
    return __uint_as_float(u & 0xffff0000u);
}

// ---------------------------------------------------------------------------
// fat front-end: [0,250) prep_rider | 250 b1eff | [251,251+KVP_BLKS) kvp |
// then SB hist2 blocks.  All four mutually independent.
// ---------------------------------------------------------------------------
__global__ __launch_bounds__(256) void k_front(
    const float* __restrict__ xr,
    const float* __restrict__ Wq, const float* __restrict__ bq,
    const float* __restrict__ Wskip, const float* __restrict__ bskip,
    const float* __restrict__ We,
    float* __restrict__ q, float* __restrict__ skip, float* __restrict__ t,
    const float* __restrict__ W1, const float* __restrict__ b1,
    const float* __restrict__ omega, float* __restrict__ b1eff,
    const float* __restrict__ x,
    const float* __restrict__ Wk, const float* __restrict__ bk,
    const float* __restrict__ Wv, const float* __restrict__ bv,
    const float* __restrict__ Wp, const float* __restrict__ bp,
    unsigned short* __restrict__ kb, unsigned short* __restrict__ vb,
    unsigned short* __restrict__ pb,
    const int* __restrict__ ridx, int* __restrict__ ghist)
{
    __shared__ __align__(16) char smem[9216];
    const int tid = threadIdx.x;
    const int b = blockIdx.x;

    if (b < 250) {
        // ---------------- prep_rider ----------------
        float* sx = (float*)smem;            // [4][32]
        float* sq = sx + 128;                // [4][64]
        int rbase = b * 4;
        if (tid < 128) {
            int rl = tid >> 5, d = tid & 31;
            sx[rl * 32 + d] = xr[(rbase + rl) * 32 + d];
        }
        __syncthreads();
        int rl = tid >> 6, h = tid & 63;
        int r = rbase + rl;
        float aq = bq[h], as = bskip[h];
        #pragma unroll 4
        for (int d = 0; d < 32; ++d) {
            float xv = sx[rl * 32 + d];
            aq += xv * Wq[d * 64 + h];
            as += xv * Wskip[d * 64 + h];
        }
        sq[rl * 64 + h] = aq;
        q[r * 64 + h] = aq;
        skip[r * 64 + h] = as;
        __syncthreads();
        if (tid < 16) {
            int rl2 = tid >> 2, d = tid & 3;
            float acc = 0.f;
            for (int hh = 0; hh < 64; ++hh)
                acc += We[d * 64 + hh] * sq[rl2 * 64 + hh];
            t[(rbase + rl2) * 4 + d] = acc;
        }
    } else if (b == 250) {
        // ---------------- b1eff ----------------
        if (tid < 128) {
            float acc = b1[tid];
            #pragma unroll 4
            for (int j = 0; j < 32; ++j)
                acc += omega[j] * W1[(128 + j) * 128 + tid];
            b1eff[tid] = acc;
        }
    } else if (b < 251 + KVP_BLKS) {
        // ---------------- kvp (bf16 MFMA) ----------------
        unsigned short* sX = (unsigned short*)smem;   // 64*72
        const int wave = tid >> 6, lane = tid & 63;
        const int l15 = lane & 15, quad = lane >> 4;

        bf16x8 bfr[3][2];
        float bias[3];
        unsigned short* outT[3];
        int colc[3];
        #pragma unroll
        for (int ct = 0; ct < 3; ++ct) {
            int n = wave * 48 + ct * 16 + l15;
            int table = n >> 6, c = n & 63;
            const float* W  = (table == 0) ? Wk : (table == 1) ? Wv : Wp;
            const float* bb = (table == 0) ? bk : (table == 1) ? bv : bp;
            bias[ct] = bb[c];
            colc[ct] = c;
            outT[ct] = (table == 0) ? kb : (table == 1) ? vb : pb;
            #pragma unroll
            for (int kf = 0; kf < 2; ++kf) {
                bf16x8 f;
                #pragma unroll
                for (int j = 0; j < 8; ++j)
                    f[j] = (short)bfu(W[(size_t)(kf * 32 + quad * 8 + j) * 64 + c]);
                bfr[ct][kf] = f;
            }
        }

        const int srl = tid >> 2;
        const int sqt = (tid & 3) * 16;

        for (int tile = b - 251; tile < KVP_TILES; tile += KVP_BLKS) {
            int rowbase = tile * 64;
            {
                int row = rowbase + srl;
                unsigned short* dst = sX + srl * 72 + sqt;
                if (row < NO_N) {
                    const float4* src = (const float4*)(x + (size_t)row * 64 + sqt);
                    #pragma unroll
                    for (int i = 0; i < 4; ++i) {
                        float4 a = src[i];
                        ushort4 u = { bfu(a.x), bfu(a.y), bfu(a.z), bfu(a.w) };
                        *(ushort4*)(dst + i * 4) = u;
                    }
                } else {
                    ushort4 z = {0, 0, 0, 0};
                    #pragma unroll
                    for (int i = 0; i < 4; ++i) *(ushort4*)(dst + i * 4) = z;
                }
            }
            __syncthreads();

            floatx4 acc[4][3];
            #pragma unroll
            for (int rt = 0; rt < 4; ++rt)
                #pragma unroll
                for (int ct = 0; ct < 3; ++ct)
                    acc[rt][ct] = (floatx4){bias[ct], bias[ct], bias[ct], bias[ct]};

            #pragma unroll
            for (int rt = 0; rt < 4; ++rt) {
                const unsigned short* ar = sX + (size_t)(rt * 16 + l15) * 72 + quad * 8;
                bf16x8 a0 = *(const bf16x8*)(ar);
                bf16x8 a1 = *(const bf16x8*)(ar + 32);
                #pragma unroll
                for (int ct = 0; ct < 3; ++ct) {
                    floatx4 c = acc[rt][ct];
                    c = __builtin_amdgcn_mfma_f32_16x16x32_bf16(a0, bfr[ct][0], c, 0, 0, 0);
                    c = __builtin_amdgcn_mfma_f32_16x16x32_bf16(a1, bfr[ct][1], c, 0, 0, 0);
                    acc[rt][ct] = c;
                }
            }

            #pragma unroll
            for (int rt = 0; rt < 4; ++rt) {
                int rb = rowbase + rt * 16 + quad * 4;
                #pragma unroll
                for (int ct = 0; ct < 3; ++ct) {
                    unsigned short* o = outT[ct];
                    size_t cbase = colc[ct];
                    #pragma unroll
                    for (int g = 0; g < 4; ++g) {
                        int row = rb + g;
                        if (row < NO_N)
                            o[(size_t)row * 64 + cbase] = bfu(acc[rt][ct][g]);
                    }
                }
            }
            __syncthreads();
        }
    } else {
        // ---------------- hist2 ----------------
        int* hc = (int*)smem;                 // [NR_N]
        int hb = b - (251 + KVP_BLKS);
        for (int i = tid; i < NR_N; i += 256) hc[i] = 0;
        __syncthreads();
        int s = hb * SCHUNK;
        for (int i = s + tid; i < s + SCHUNK; i += 256)
            atomicAdd(&hc[ridx[i]], 1);
        __syncthreads();
        for (int i = tid; i < NR_N; i += 256)
            ghist[i * SB + hb] = hc[i];
    }
}

// ---------------------------------------------------------------------------
__global__ __launch_bounds__(256) void k_colscan(const int* __restrict__ ghist,
                                                 int* __restrict__ gpre,
                                                 int* __restrict__ counts)
{
    __shared__ int s[256];
    int tid = threadIdx.x, r = blockIdx.x;
    int v = (tid < SB) ? ghist[r * SB + tid] : 0;
    s[tid] = v;
    __syncthreads();
    for (int off = 1; off < 256; off <<= 1) {
        int tv = (tid >= off) ? s[tid - off] : 0;
        __syncthreads();
        s[tid] += tv;
        __syncthreads();
    }
    if (tid < SB) gpre[r * SB + tid] = s[tid] - v;
    if (tid == 255) counts[r] = s[255];
}

// scan over riders -> offsets + tilestart (trec fill moved to k_trec)
__global__ __launch_bounds__(1024) void k_scan(const int* __restrict__ counts,
                                               int* __restrict__ offsets,
                                               int* __restrict__ tilestart)
{
    __shared__ int s[1024];
    int tid = threadIdx.x;
    int c = (tid < NR_N) ? counts[tid] : 0;
    s[tid] = c;
    __syncthreads();
    for (int off = 1; off < 1024; off <<= 1) {
        int tv = (tid >= off) ? s[tid - off] : 0;
        __syncthreads();
        s[tid] += tv;
        __syncthreads();
    }
    if (tid < NR_N) offsets[tid] = s[tid] - c;
    if (tid == NR_N - 1) offsets[NR_N] = s[tid];
    __syncthreads();
    int tc = (tid < NR_N) ? ((c + 63) >> 6) : 0;
    s[tid] = tc;
    __syncthreads();
    for (int off = 1; off < 1024; off <<= 1) {
        int tv = (tid >= off) ? s[tid - off] : 0;
        __syncthreads();
        s[tid] += tv;
        __syncthreads();
    }
    if (tid < NR_N) tilestart[tid] = s[tid] - tc;
    if (tid == NR_N - 1) tilestart[NR_N] = s[tid];
}

// parallel trec fill: trec[t] = {r, jb, jend} via binary search (L2-hot)
__global__ __launch_bounds__(256) void k_trec(const int* __restrict__ tilestart,
                                              const int* __restrict__ offsets,
                                              int4* __restrict__ trec)
{
    int nt = tilestart[NR_N];
    int t = blockIdx.x * 256 + threadIdx.x;
    if (t >= nt) return;
    int lo = 0, hi = NR_N - 1;
    while (lo < hi) {                 // largest r with tilestart[r] <= t
        int mid = (lo + hi + 1) >> 1;
        if (tilestart[mid] <= t) lo = mid; else hi = mid - 1;
    }
    trec[t] = make_int4(lo, offsets[lo] + ((t - tilestart[lo]) << 6),
                        offsets[lo + 1], 0);
}

// ---------------------------------------------------------------------------
// scatter: spack (k_rider), so (k_edge2), rank (k_perm, coalesced in i)
// ---------------------------------------------------------------------------
__global__ __launch_bounds__(256) void k_scatter2(
    const int* __restrict__ ridx, const int* __restrict__ oidx,
    const float* __restrict__ ea, const float* __restrict__ t,
    const int* __restrict__ offsets, const int* __restrict__ gpre,
    int4* __restrict__ spack, int* __restrict__ so, int* __restrict__ rank)
{
    __shared__ int cur[NR_N];
    int tid = threadIdx.x, b = blockIdx.x;
    for (int i = tid; i < NR_N; i += 256)
        cur[i] = offsets[i] + gpre[i * SB + b];
    __syncthreads();
    int s = b * SCHUNK;
    for (int i = s + tid; i < s + SCHUNK; i += 256) {
        int r = ridx[i];
        int o = oidx[i];
        float4 e4 = *(const float4*)(ea + (size_t)i * 4);
        float4 t4 = *(const float4*)(t + r * 4);
        float h = e4.x * t4.x + e4.y * t4.y + e4.z * t4.z + e4.w * t4.w;
        int pos = atomicAdd(&cur[r], 1);
        int4 pk;
        pk.x = o;
        pk.y = __float_as_int(h);
        pk.z = (int)((unsigned)bfu(e4.x) | ((unsigned)bfu(e4.y) << 16));
        pk.w = (int)((unsigned)bfu(e4.z) | ((unsigned)bfu(e4.w) << 16));
        spack[pos] = pk;
        so[pos] = o;
        rank[i] = pos;
    }
}

// ---------------------------------------------------------------------------
// rider embedding + fused Br; emits emb in bf16 (embb) for k_edge2's
// MFMA-fused dot column. 512 threads (8 waves).
// ---------------------------------------------------------------------------
__global__ __launch_bounds__(512) void k_rider(
    const int* __restrict__ offsets, const int4* __restrict__ spack,
    const float* __restrict__ q,
    const unsigned short* __restrict__ kb, const unsigned short* __restrict__ vb,
    const float* __restrict__ We, const float* __restrict__ skip,
    const float* __restrict__ W1, const float* __restrict__ b1eff,
    unsigned short* __restrict__ embb, float* __restrict__ Br)
{
    __shared__ float sQ[64];
    __shared__ int2 sOX[8][64];
    __shared__ float rv[8][64];
    __shared__ float re4[8][4];
    __shared__ float rd[8];

    int r = blockIdx.x;
    int wave = threadIdx.x >> 6, lane = threadIdx.x & 63;
    if (threadIdx.x < 64) sQ[threadIdx.x] = q[r * 64 + threadIdx.x];
    __syncthreads();

    int beg = offsets[r], end = offsets[r + 1];
    int cnt = end - beg;
    int chunk = (cnt + 7) >> 3;
    int s0 = beg + wave * chunk;
    int s1 = min(s0 + chunk, end);

    float aggv = 0.f, dsum = 0.f;
    float ag0 = 0.f, ag1 = 0.f, ag2 = 0.f, ag3 = 0.f;
    const float2* sQ2 = (const float2*)sQ;

    for (int jb = s0; jb < s1; jb += 64) {
        int j = jb + lane;
        bool valid = (j < s1);
        int4 pk = make_int4(0, 0, 0, 0);
        if (valid) pk = spack[j];
        int oo = pk.x;
        float h = __int_as_float(pk.y);

        const uint4* krow = (const uint4*)(kb + (size_t)oo * 64);
        uint4 K0 = krow[0], K1 = krow[1], K2 = krow[2], K3 = krow[3];
        uint4 K4 = krow[4], K5 = krow[5], K6 = krow[6], K7 = krow[7];
        float acc = h;
        #define DOT8(Kv, base) { \
            float2 qa = sQ2[(base) + 0]; \
            acc = fmaf(bflo(Kv.x), qa.x, acc); acc = fmaf(bfhi(Kv.x), qa.y, acc); \
            float2 qb = sQ2[(base) + 1]; \
            acc = fmaf(bflo(Kv.y), qb.x, acc); acc = fmaf(bfhi(Kv.y), qb.y, acc); \
            float2 qc = sQ2[(base) + 2]; \
            acc = fmaf(bflo(Kv.z), qc.x, acc); acc = fmaf(bfhi(Kv.z), qc.y, acc); \
            float2 qd = sQ2[(base) + 3]; \
            acc = fmaf(bflo(Kv.w), qd.x, acc); acc = fmaf(bfhi(Kv.w), qd.y, acc); }
        DOT8(K0, 0) DOT8(K1, 4) DOT8(K2, 8) DOT8(K3, 12)
        DOT8(K4, 16) DOT8(K5, 20) DOT8(K6, 24) DOT8(K7, 28)
        #undef DOT8

        float exv = valid ? __expf(acc * 0.125f) : 0.f;
        dsum += exv;
        unsigned int ez = (unsigned int)pk.z, ew = (unsigned int)pk.w;
        ag0 = fmaf(exv, bflo(ez), ag0);
        ag1 = fmaf(exv, bfhi(ez), ag1);
        ag2 = fmaf(exv, bflo(ew), ag2);
        ag3 = fmaf(exv, bfhi(ew), ag3);

        sOX[wave][lane] = make_int2(oo, __float_as_int(exv));

        int nn = min(s1 - jb, 64);
        int i = 0;
        for (; i + 8 <= nn; i += 8) {
            int2 x0 = sOX[wave][i + 0], x1 = sOX[wave][i + 1];
            int2 x2 = sOX[wave][i + 2], x3 = sOX[wave][i + 3];
            int2 x4 = sOX[wave][i + 4], x5 = sOX[wave][i + 5];
            int2 x6 = sOX[wave][i + 6], x7 = sOX[wave][i + 7];
            unsigned short u0 = vb[(size_t)x0.x * 64 + lane];
            unsigned short u1 = vb[(size_t)x1.x * 64 + lane];
            unsigned short u2 = vb[(size_t)x2.x * 64 + lane];
            unsigned short u3 = vb[(size_t)x3.x * 64 + lane];
            unsigned short u4 = vb[(size_t)x4.x * 64 + lane];
            unsigned short u5 = vb[(size_t)x5.x * 64 + lane];
            unsigned short u6 = vb[(size_t)x6.x * 64 + lane];
            unsigned short u7 = vb[(size_t)x7.x * 64 + lane];
            aggv = fmaf(__int_as_float(x0.y), __uint_as_float((unsigned int)u0 << 16), aggv);
            aggv = fmaf(__int_as_float(x1.y), __uint_as_float((unsigned int)u1 << 16), aggv);
            aggv = fmaf(__int_as_float(x2.y), __uint_as_float((unsigned int)u2 << 16), aggv);
            aggv = fmaf(__int_as_float(x3.y), __uint_as_float((unsigned int)u3 << 16), aggv);
            aggv = fmaf(__int_as_float(x4.y), __uint_as_float((unsigned int)u4 << 16), aggv);
            aggv = fmaf(__int_as_float(x5.y), __uint_as_float((unsigned int)u5 << 16), aggv);
            aggv = fmaf(__int_as_float(x6.y), __uint_as_float((unsigned int)u6 << 16), aggv);
            aggv = fmaf(__int_as_float(x7.y), __uint_as_float((unsigned int)u7 << 16), aggv);
        }
        for (; i < nn; ++i) {
            int2 xx = sOX[wave][i];
            unsigned short uu = vb[(size_t)xx.x * 64 + lane];
            aggv = fmaf(__int_as_float(xx.y), __uint_as_float((unsigned int)uu << 16), aggv);
        }
    }

    #pragma unroll
    for (int m = 1; m < 64; m <<= 1) {
        dsum += __shfl_xor(dsum, m);
        ag0 += __shfl_xor(ag0, m);
        ag1 += __shfl_xor(ag1, m);
        ag2 += __shfl_xor(ag2, m);
        ag3 += __shfl_xor(ag3, m);
    }

    rv[wave][lane] = aggv;
    if (lane == 0) {
        rd[wave] = dsum;
        re4[wave][0] = ag0; re4[wave][1] = ag1;
        re4[wave][2] = ag2; re4[wave][3] = ag3;
    }
    __syncthreads();
    if (threadIdx.x < 64) {
        int l = threadIdx.x;
        float av = 0.f, ds = 0.f, a0 = 0.f, a1 = 0.f, a2 = 0.f, a3 = 0.f;
        #pragma unroll
        for (int w = 0; w < 8; ++w) {
            av += rv[w][l]; ds += rd[w];
            a0 += re4[w][0]; a1 += re4[w][1]; a2 += re4[w][2]; a3 += re4[w][3];
        }
        float corr = a0 * We[0 * 64 + l] + a1 * We[1 * 64 + l]
                   + a2 * We[2 * 64 + l] + a3 * We[3 * 64 + l];
        float val = (av + corr) / (ds + 1e-16f) + skip[r * 64 + l];
        embb[r * 64 + l] = bfu(val);
        sQ[l] = val;                      // reuse sQ as emb row (f32 for Br)
    }
    __syncthreads();
    // fused Br: col c = tid (<128)
    if (threadIdx.x < 128) {
        int c = threadIdx.x;
        float a = b1eff[c];
        #pragma unroll 8
        for (int d = 0; d < 64; ++d)
            a = fmaf(sQ[d], W1[(size_t)(64 + d) * 128 + c], a);
        Br[r * 128 + c] = a;
    }
}

// ---------------------------------------------------------------------------
// per-edge scoring: wave-per-tile, direct global->MFMA A-fragment gathers
// (r14 pattern). NEW: the dot(oe,emb) term is computed BY the MFMA via a 9th
// column-tile whose col 0 = embb[r] (cols 1-15 zero) — no VALU dot, no
// shuffles; the result lands in C-layout exactly on the storing lanes.
// ---------------------------------------------------------------------------
__global__ __launch_bounds__(256) void k_edge2(
    const int* __restrict__ so, const int4* __restrict__ trec,
    const int* __restrict__ tilestart,
    const unsigned short* __restrict__ pb, const unsigned short* __restrict__ embb,
    const float* __restrict__ Br, const float* __restrict__ W1,
    const float* __restrict__ W2, const float* __restrict__ b2,
    float* __restrict__ tmp)
{
    __shared__ __align__(16) unsigned short sW[128 * 72];  // W1a^T bf16

    const int tid = threadIdx.x;
    const int wave = tid >> 6;
    const int lane = tid & 63;
    const int l15 = lane & 15;
    const int quad = lane >> 4;

    // ---- setup: coalesced W1 -> LDS transpose -> ds_read_b128 fragments ----
    for (int idx = tid; idx < 64 * 128; idx += 256) {
        int k = idx >> 7, n = idx & 127;
        sW[n * 72 + k] = bfu(W1[idx]);
    }
    __syncthreads();

    bf16x8 bfr[8][2];
    float w2v[8];
    #pragma unroll
    for (int ctl = 0; ctl < 8; ++ctl) {
        int n = ctl * 16 + l15;
        w2v[ctl] = W2[n];
        #pragma unroll
        for (int kc = 0; kc < 2; ++kc)
            bfr[ctl][kc] = *(const bf16x8*)(sW + n * 72 + kc * 32 + quad * 8);
    }
    float b2v = b2[0];
    const int ntiles = tilestart[NR_N];
    const bf16x8 z8 = (bf16x8){0, 0, 0, 0, 0, 0, 0, 0};

    union U4B { uint4 u; bf16x8 b; };

    for (int tile = blockIdx.x * 4 + wave; tile < ntiles; tile += gridDim.x * 4) {
        int4 rr = trec[tile];
        const int r = rr.x, jb = rr.y, jend = rr.z;

        // ---- edge ids (coalesced), then direct A-fragment gathers ----
        int o_l = so[min(jb + lane, jend - 1)];
        U4B A0[4], A1[4];
        #pragma unroll
        for (int rt = 0; rt < 4; ++rt) {
            int osrc = __shfl(o_l, rt * 16 + l15);
            const unsigned short* rowp = pb + (size_t)osrc * 64 + quad * 8;
            A0[rt].u = *(const uint4*)(rowp);        // dims quad*8 .. +8
            A1[rt].u = *(const uint4*)(rowp + 32);   // dims 32+quad*8 .. +8
        }

        // ---- 9th B column-tile: col 0 = embb[r] (bf16), cols 1-15 zero ----
        const unsigned short* eb = embb + r * 64;
        bf16x8 e0 = *(const bf16x8*)(eb + quad * 8);        // L1-hot
        bf16x8 e1 = *(const bf16x8*)(eb + 32 + quad * 8);
        bf16x8 b80 = z8, b81 = z8;
        if (l15 == 0) { b80 = e0; b81 = e1; }

        // rider-uniform Br slice (L1/L2-hot)
        float brv[8];
        #pragma unroll
        for (int ctl = 0; ctl < 8; ++ctl)
            brv[ctl] = Br[r * 128 + ctl * 16 + l15];

        // ---- MFMA + fused relu/W2 epilogue per row-tile ----
        #pragma unroll
        for (int rt = 0; rt < 4; ++rt) {
            floatx4 s = (floatx4){0.f, 0.f, 0.f, 0.f};
            #pragma unroll
            for (int ctl = 0; ctl < 8; ++ctl) {
                floatx4 c = (floatx4){0.f, 0.f, 0.f, 0.f};
                c = __builtin_amdgcn_mfma_f32_16x16x32_bf16(A0[rt].b, bfr[ctl][0], c, 0, 0, 0);
                c = __builtin_amdgcn_mfma_f32_16x16x32_bf16(A1[rt].b, bfr[ctl][1], c, 0, 0, 0);
                #pragma unroll
                for (int g = 0; g < 4; ++g)
                    s[g] = fmaf(fmaxf(c[g] + brv[ctl], 0.f), w2v[ctl], s[g]);
            }
            // dot column: D[row][0] on lanes l15==0, row = quad*4+g
            floatx4 c8 = (floatx4){0.f, 0.f, 0.f, 0.f};
            c8 = __builtin_amdgcn_mfma_f32_16x16x32_bf16(A0[rt].b, b80, c8, 0, 0, 0);
            c8 = __builtin_amdgcn_mfma_f32_16x16x32_bf16(A1[rt].b, b81, c8, 0, 0, 0);

            #pragma unroll
            for (int m = 1; m < 16; m <<= 1) {
                s[0] += __shfl_xor(s[0], m);
                s[1] += __shfl_xor(s[1], m);
                s[2] += __shfl_xor(s[2], m);
                s[3] += __shfl_xor(s[3], m);
            }
            if (l15 == 0) {
                int rowb = rt * 16 + quad * 4;
                #pragma unroll
                for (int g = 0; g < 4; ++g) {
                    int pos = jb + rowb + g;
                    if (pos < jend) {
                        float v = s[g] + 0.125f * c8[g] + b2v;
                        tmp[pos] = fminf(fmaxf(v, -10.f), 10.f);
                    }
                }
            }
        }
    }
}

// ---------------------------------------------------------------------------
// out[i] = tmp[rank[i]]  (rank coalesced read, tmp L2-resident gather)
// ---------------------------------------------------------------------------
__global__ __launch_bounds__(256) void k_perm(const int* __restrict__ rank,
                                              const float* __restrict__ tmp,
                                              float* __restrict__ out)
{
    int i = blockIdx.x * 256 + threadIdx.x;
    if (i < E_N) out[i] = tmp[rank[i]];
}

// ---------------------------------------------------------------------------
extern "C" void kernel_launch(void* const* d_in, const int* in_sizes, int n_in,
                              void* d_out, int out_size, void* d_ws, size_t ws_size,
                              hipStream_t stream)
{
    const float* x_order   = (const float*)d_in[0];
    const float* x_rider   = (const float*)d_in[1];
    const float* edge_attr = (const float*)d_in[2];
    const int*   order_idx = (const int*)d_in[3];
    const int*   rider_idx = (const int*)d_in[4];
    const float* omega     = (const float*)d_in[5];
    const float* Wk = (const float*)d_in[6];  const float* bk = (const float*)d_in[7];
    const float* Wq = (const float*)d_in[8];  const float* bq = (const float*)d_in[9];
    const float* Wv = (const float*)d_in[10]; const float* bv = (const float*)d_in[11];
    const float* We = (const float*)d_in[12];
    const float* Wskip = (const float*)d_in[13]; const float* bskip = (const float*)d_in[14];
    const float* Wp = (const float*)d_in[15]; const float* bp = (const float*)d_in[16];
    const float* W1 = (const float*)d_in[17]; const float* b1 = (const float*)d_in[18];
    const float* W2 = (const float*)d_in[19]; const float* b2 = (const float*)d_in[20];
    float* out = (float*)d_out;

    unsigned short* ws_kb = (unsigned short*)d_ws;
    unsigned short* ws_vb = ws_kb + (size_t)NO_N * 64;
    unsigned short* ws_pb = ws_vb + (size_t)NO_N * 64;
    int4* ws_spack = (int4*)(ws_pb + (size_t)NO_N * 64);
    float* ws_tmp  = (float*)ws_spack;              // alias: spack dead by k_edge2
    int*  ws_so    = (int*)(ws_spack + E_N);
    int*  ws_rank  = ws_so + E_N;
    float* wsf     = (float*)(ws_rank + E_N);
    float* ws_q    = wsf;
    float* ws_skip = ws_q + NR_N * 64;
    unsigned short* ws_embb = (unsigned short*)(ws_skip + NR_N * 64);  // bf16 emb
    float* ws_t    = (float*)(ws_embb + NR_N * 64);
    float* ws_b1e  = ws_t + NR_N * 4;
    float* ws_Br   = ws_b1e + 128;
    int* ws_counts  = (int*)(ws_Br + NR_N * 128);
    int* ws_offsets = ws_counts + NR_N;
    int* ws_tilest  = ws_offsets + NR_N + 8;
    int* ws_ghist   = ws_tilest + NR_N + 8;
    int* ws_gpre    = ws_ghist + NR_N * SB;
    int4* ws_trec   = (int4*)(((uintptr_t)(ws_gpre + NR_N * SB) + 15) & ~(uintptr_t)15);

    k_front<<<251 + KVP_BLKS + SB, 256, 0, stream>>>(
        x_rider, Wq, bq, Wskip, bskip, We, ws_q, ws_skip, ws_t,
        W1, b1, omega, ws_b1e,
        x_order, Wk, bk, Wv, bv, Wp, bp, ws_kb, ws_vb, ws_pb,
        rider_idx, ws_ghist);
    k_colscan<<<NR_N, 256, 0, stream>>>(ws_ghist, ws_gpre, ws_counts);
    k_scan<<<1, 1024, 0, stream>>>(ws_counts, ws_offsets, ws_tilest);
    k_trec<<<(MAXTILES + 255) / 256, 256, 0, stream>>>(ws_tilest, ws_offsets, ws_trec);
    k_scatter2<<<SB, 256, 0, stream>>>(rider_idx, order_idx, edge_attr, ws_t,
                                       ws_offsets, ws_gpre, ws_spack, ws_so, ws_rank);
    k_rider<<<NR_N, 512, 0, stream>>>(ws_offsets, ws_spack, ws_q,
                                      ws_kb, ws_vb, We, ws_skip,
                                      W1, ws_b1e, ws_embb, ws_Br);
    k_edge2<<<1024, 256, 0, stream>>>(ws_so, ws_trec, ws_tilest,
                                      ws_pb, ws_embb, ws_Br, W1, W2, b2, ws_tmp);
    k_perm<<<(E_N + 255) / 256, 256, 0, stream>>>(ws_rank, ws_tmp, out);
}